// Round 11
// baseline (168.748 us; speedup 1.0000x reference)
//
#include <hip/hip_runtime.h>

namespace {

constexpr int NV = 512;
typedef unsigned long long ull;
constexpr ull INF64 = ~0ULL;
constexpr unsigned WMAX = 0xFFFFFFFFu;

// Edge total order = reference's stable sort: (f32 weight bits, triu index).
// triu index is order-isomorphic to lex (i,j), i<j, so the canonical key
// (w_bits<<32)|(i<<9)|j induces the identical order (w>=0 -> bits monotone).
// Keys globally unique -> unique MST -> Boruvka accepts exactly Kruskal's set.
//
// Base = R3 (measured best, 97us bench / ~105us kernel), with ONLY merge-fat
// removed, guided by R8/R9 measurements:
//   1. pointer-jump loop exits adaptively (no-change pass == proof of full
//      compression; stamp check is uniform; cap 9 kept)
//   2. 2-cycle-break + accept folded into one phase (accept touches no parent)
//   3. accept's same-address atomicAdd storm -> ballot+popcount per wave
// Scan phase and everything else: R3 verbatim. Root-walk NOT used (R8: +70us).
__global__ __launch_bounds__(1024) void boruvka_loss(
    const float* __restrict__ d1, const float* __restrict__ d2,
    float* __restrict__ partial)
{
    const int blk = blockIdx.x;
    const float* __restrict__ Dm = blk ? d2 : d1;
    const float* __restrict__ Do = blk ? d1 : d2;
    const int tid = threadIdx.x;
    const int lane = tid & 63;
    const int wid = tid >> 6;

    __shared__ __align__(16) unsigned comp[NV];   // vertex -> component root
    __shared__ ull best[NV];                      // per-component min out-edge key
    __shared__ unsigned parent[NV];               // hook forest
    __shared__ int waveAcc[16];
    __shared__ float red[16];
    __shared__ int accTot;
    __shared__ int jflag;                         // jump-pass change stamp

    if (tid < NV) { comp[tid] = tid; best[tid] = INF64; }
    if (tid == 0) { accTot = 0; jflag = -1; }

    const int v  = tid >> 1;               // 2 threads per row
    const int c0 = (tid & 1) << 8;         // column half 0 / 256
    const float4* __restrict__ rowp4 =
        reinterpret_cast<const float4*>(Dm + ((size_t)v << 9) + c0);
    const uint4* comp4 = reinterpret_cast<const uint4*>(&comp[c0]);

    float contrib = 0.f;

    __syncthreads();

    for (int round = 0; round < 10; ++round) {
        // ---- scan (R3 verbatim): first-wins ascending keeps the canonical
        // smallest column among equal weights within this half-row
        {
            const unsigned cv = comp[v];
            unsigned wmin = WMAX, umin = 0;
            bool any = false;
#pragma unroll 4
            for (int s = 0; s < 64; ++s) {
                float4 w4 = rowp4[s];
                uint4  q4 = comp4[s];
                unsigned wb;
                wb = __float_as_uint(w4.x);
                if ((q4.x != cv) && (!any || wb < wmin)) { wmin = wb; umin = c0 + s*4 + 0; any = true; }
                wb = __float_as_uint(w4.y);
                if ((q4.y != cv) && (wb < wmin || !any)) { wmin = wb; umin = c0 + s*4 + 1; any = true; }
                wb = __float_as_uint(w4.z);
                if ((q4.z != cv) && (wb < wmin || !any)) { wmin = wb; umin = c0 + s*4 + 2; any = true; }
                wb = __float_as_uint(w4.w);
                if ((q4.w != cv) && (wb < wmin || !any)) { wmin = wb; umin = c0 + s*4 + 3; any = true; }
            }
            if (any) {
                unsigned uv = (unsigned)v;
                unsigned lo = (umin < uv) ? ((umin << 9) | uv) : ((uv << 9) | umin);
                atomicMin(&best[cv], ((ull)wmin << 32) | (ull)lo);
            }
        }
        __syncthreads();                           // best final; comp stable

        // ---- hook: component t points across its best edge
        ull he = INF64; unsigned hp = 0, hlo = 0;
        if (tid < NV) {
            unsigned t = (unsigned)tid;
            he = best[t];
            hp = t;
            if (he != INF64) {
                hlo = (unsigned)he & 0x3FFFFu;
                unsigned ci = comp[hlo >> 9], cj = comp[hlo & 511u];
                hp = (ci == t) ? cj : ci;
            }
            parent[t] = hp;
        }
        __syncthreads();

        // ---- 2-cycle break + accept + count (folded; accept reads only
        // best/comp/registers, never parent -> fold is race-equivalent to R3)
        bool take = false;
        if (tid < NV) {
            unsigned t = (unsigned)tid, p = parent[t];
            if (p != t && parent[p] == t && t < p) parent[t] = t;
            if (he != INF64) {
                take = !((best[hp] == he) && (hp < t));   // dedup mutual pick
                if (take) {
                    float a = __uint_as_float((unsigned)(he >> 32)); // Dm[i][j]
                    float b = Do[hlo];                  // (i<<9)|j == i*512+j
                    float d = a - b;
                    contrib += d * d;
                }
            }
        }
        {
            ull bal = __ballot(take);
            if (lane == 0) waveAcc[wid] = __popcll(bal);
        }
        __syncthreads();

        // ---- adaptive pointer jumping (<=9 passes; each pass only writes
        // when it changes something; a no-change pass is read-race-free and
        // proves parent o parent == parent, i.e. full compression)
        for (int jt = 0; jt < 9; ++jt) {
            bool chg = false;
            if (tid < NV) {
                unsigned p = parent[tid];
                unsigned np = parent[p];
                if (np != p) { parent[tid] = np; chg = true; }
            }
            const int stamp = (round << 4) | (jt + 1);  // unique across kernel
            if (__ballot(chg) != 0ull && lane == 0) jflag = stamp;
            __syncthreads();
            if (jflag != stamp) break;                  // uniform post-barrier
        }

        // ---- relabel + reset + termination count
        if (tid < NV) {
            comp[tid] = parent[comp[tid]];
            best[tid] = INF64;
        }
        if (tid == 0) {
            int s = 0;
#pragma unroll
            for (int w = 0; w < 16; ++w) s += waveAcc[w];
            accTot += s;
        }
        __syncthreads();
        if (accTot == NV - 1) break;                    // uniform post-barrier
    }

    // ---- deterministic reduction: wave butterfly, then fixed-order sum
#pragma unroll
    for (int off = 32; off >= 1; off >>= 1) contrib += __shfl_xor(contrib, off);
    if (lane == 0) red[wid] = contrib;
    __syncthreads();
    if (tid == 0) {
        float s = 0.f;
#pragma unroll
        for (int w = 0; w < 16; ++w) s += red[w];
        partial[blk] = s;
    }
}

__global__ void final_add(const float* __restrict__ partial, float* __restrict__ out) {
    out[0] = partial[0] + partial[1];
}

} // namespace

extern "C" void kernel_launch(void* const* d_in, const int* in_sizes, int n_in,
                              void* d_out, int out_size, void* d_ws, size_t ws_size,
                              hipStream_t stream) {
    const float* d1 = (const float*)d_in[0];
    const float* d2 = (const float*)d_in[1];
    float* out = (float*)d_out;
    float* ws = (float*)d_ws;

    boruvka_loss<<<2, 1024, 0, stream>>>(d1, d2, ws); // writes ws[0], ws[1]
    final_add<<<1, 1, 0, stream>>>(ws, out);
}

// Round 12
// 113.715 us; speedup vs baseline: 1.4840x; 1.4840x over previous
//
#include <hip/hip_runtime.h>

namespace {

constexpr int NV = 512;
typedef unsigned long long ull;
constexpr ull INF64 = ~0ULL;
constexpr unsigned WMAX = 0xFFFFFFFFu;

// Edge total order = reference's stable sort: (f32 weight bits, triu index).
// triu index is order-isomorphic to lex (i,j), i<j, so the canonical key
// (w_bits<<32)|(i<<9)|j induces the identical order (w>=0 -> bits monotone).
// Keys globally unique -> unique MST -> Boruvka accepts exactly Kruskal's set.
//
// Structure = R3 (measured best, 97us) with two conservative deltas:
//   1. 512-thread block, 1 thread = 1 full row: comp4 scan reads become
//      wave-broadcast (same address), scan atomics halve, and all merge
//      phases run all-threads-active with 8 waves per barrier (was 16).
//   2. jump passes = max(4, 9-round): depth <= C_r <= 512>>r, so 2^passes
//      still provably covers full compression. Fixed count, no flags
//      (R10's adaptive flag machinery measured +66us).
// Merge phase ORDER and bodies are R3 verbatim; atomicAdd(&accTot,1) kept
// (compiler wave-coalesces it, G12; R3/R9 with it are the two best runs).
__global__ __launch_bounds__(512) void boruvka_loss(
    const float* __restrict__ d1, const float* __restrict__ d2,
    float* __restrict__ partial)
{
    const int blk = blockIdx.x;
    const float* __restrict__ Dm = blk ? d2 : d1;
    const float* __restrict__ Do = blk ? d1 : d2;
    const int tid = threadIdx.x;
    const int lane = tid & 63;
    const int wid = tid >> 6;

    __shared__ __align__(16) unsigned comp[NV];   // vertex -> component root
    __shared__ ull best[NV];                      // per-component min out-edge key
    __shared__ unsigned parent[NV];               // hook forest
    __shared__ float red[8];
    __shared__ int accTot;

    comp[tid] = tid;
    best[tid] = INF64;
    if (tid == 0) accTot = 0;

    const float4* __restrict__ rowp4 =
        reinterpret_cast<const float4*>(Dm + ((size_t)tid << 9));
    const uint4* comp4 = reinterpret_cast<const uint4*>(&comp[0]);

    float contrib = 0.f;

    __syncthreads();

    for (int round = 0; round < 10; ++round) {
        // ---- scan (R3 body, 1 thread = full row): first-wins ascending
        // keeps the canonical smallest column among equal weights; round 0's
        // identity labels mask exactly the diagonal, same as R3.
        {
            const unsigned cv = comp[tid];
            unsigned wmin = WMAX, umin = 0;
            bool any = false;
#pragma unroll 4
            for (int s = 0; s < 128; ++s) {
                float4 w4 = rowp4[s];
                uint4  q4 = comp4[s];          // same addr across wave: broadcast
                unsigned wb;
                wb = __float_as_uint(w4.x);
                if ((q4.x != cv) && (!any || wb < wmin)) { wmin = wb; umin = s*4 + 0; any = true; }
                wb = __float_as_uint(w4.y);
                if ((q4.y != cv) && (wb < wmin || !any)) { wmin = wb; umin = s*4 + 1; any = true; }
                wb = __float_as_uint(w4.z);
                if ((q4.z != cv) && (wb < wmin || !any)) { wmin = wb; umin = s*4 + 2; any = true; }
                wb = __float_as_uint(w4.w);
                if ((q4.w != cv) && (wb < wmin || !any)) { wmin = wb; umin = s*4 + 3; any = true; }
            }
            if (any) {
                unsigned uv = (unsigned)tid;
                unsigned lo = (umin < uv) ? ((umin << 9) | uv) : ((uv << 9) | umin);
                atomicMin(&best[cv], ((ull)wmin << 32) | (ull)lo);
            }
        }
        __syncthreads();                           // best final; comp stable

        // ---- hook: component t points across its best edge
        ull he; unsigned hp, hlo = 0;
        {
            unsigned t = (unsigned)tid;
            he = best[t];
            hp = t;
            if (he != INF64) {
                hlo = (unsigned)he & 0x3FFFFu;
                unsigned ci = comp[hlo >> 9], cj = comp[hlo & 511u];
                hp = (ci == t) ? cj : ci;
            }
            parent[t] = hp;
        }
        __syncthreads();

        // ---- break 2-cycles: smaller id of a mutual pair becomes root
        {
            unsigned t = (unsigned)tid, p = parent[t];
            if (p != t && parent[p] == t && t < p) parent[t] = t;
        }
        __syncthreads();

        // ---- accept (dedup mutual picks via unique key)
        if (he != INF64) {
            bool dup = (best[hp] == he) && (hp < (unsigned)tid);
            if (!dup) {
                float a = __uint_as_float((unsigned)(he >> 32)); // Dm[i][j]
                float b = Do[hlo];                 // (i<<9)|j == i*512+j
                float d = a - b;
                contrib += d * d;
                atomicAdd(&accTot, 1);             // wave-coalesced by compiler
            }
        }

        // ---- pointer jumping: passes = max(4, 9-round); depth <= C_r <=
        // 512>>r so 2^passes >= C_r always fully compresses. Fixed count.
        {
            int passes = 9 - round;
            if (passes < 4) passes = 4;
            for (int jt = 0; jt < passes; ++jt) {
                __syncthreads();
                parent[tid] = parent[parent[tid]];
            }
        }
        __syncthreads();

        // ---- relabel + reset
        comp[tid] = parent[comp[tid]];
        best[tid] = INF64;
        __syncthreads();

        if (accTot == NV - 1) break;               // uniform post-barrier
    }

    // ---- deterministic reduction: wave butterfly, then fixed-order sum
#pragma unroll
    for (int off = 32; off >= 1; off >>= 1) contrib += __shfl_xor(contrib, off);
    if (lane == 0) red[wid] = contrib;
    __syncthreads();
    if (tid == 0) {
        float s = 0.f;
#pragma unroll
        for (int w = 0; w < 8; ++w) s += red[w];
        partial[blk] = s;
    }
}

__global__ void final_add(const float* __restrict__ partial, float* __restrict__ out) {
    out[0] = partial[0] + partial[1];
}

} // namespace

extern "C" void kernel_launch(void* const* d_in, const int* in_sizes, int n_in,
                              void* d_out, int out_size, void* d_ws, size_t ws_size,
                              hipStream_t stream) {
    const float* d1 = (const float*)d_in[0];
    const float* d2 = (const float*)d_in[1];
    float* out = (float*)d_out;
    float* ws = (float*)d_ws;

    boruvka_loss<<<2, 512, 0, stream>>>(d1, d2, ws); // writes ws[0], ws[1]
    final_add<<<1, 1, 0, stream>>>(ws, out);
}